// Round 11
// baseline (47.998 us; speedup 1.0000x reference)
//
#include <hip/hip_runtime.h>
#include <math.h>
#include <float.h>

// Problem constants (match reference setup_inputs)
#define BB 8
#define NN 2048
#define BN (BB * NN)
#define BLK 256
#define Q 8                      // queries per thread (wave-uniform: wave owns 8)
#define QPB 32                   // queries per block (4 waves x 8)
#define NQS (NN / QPB)           // 64 query-slices per (task,b)
#define NBLOCKS (2 * BB * NQS)   // 1024 blocks: 4 blocks/CU (32KB LDS each)

// Workspace layout. cham/l1p/cnt are written via RELEASE atomic stores and read
// via ACQUIRE atomic loads (r3-r10 proven pattern). gcnt is MONOTONIC: only
// (ticket+1) mod NBLOCKS is tested, so no init needed, 0xAA poison harmless.
//   float cham[1024]  @ 0
//   float l1p[512]    @ 4096
//   float cnt[512]    @ 6144
//   uint  gcnt        @ 8192
__global__ __launch_bounds__(BLK, 4) void k_one(const float* __restrict__ pred,
                                                const float* __restrict__ target,
                                                const float* __restrict__ points,
                                                const int* __restrict__ mask,
                                                float* __restrict__ cham,
                                                float* __restrict__ l1p,
                                                float* __restrict__ cnt,
                                                unsigned int* __restrict__ gcnt,
                                                float* __restrict__ out) {
    // bid = (task<<9) | (b<<6) | qs   -> 1024 blocks
    int bid = blockIdx.x;
    int qs = bid & (NQS - 1);
    int b = (bid >> 6) & 7;
    int task = bid >> 9;   // 0: query=clean(points+target), cand=predp(points+pred)
                           // 1: query=predp,               cand=clean
    int t = threadIdx.x;
    int lane = t & 63, w = t >> 6;

    const float* dq = task ? pred : target;   // query delta
    const float* dc = task ? target : pred;   // candidate delta

    // ---- stage ALL 2048 candidates of (task,b) into LDS (32 KB) ----
    // interleaved j = c*BLK + t -> ds_write_b128 is wave-contiguous, conflict-free
    __shared__ float4 cand[NN];
    #pragma unroll
    for (int c = 0; c < NN / BLK; ++c) {
        int j = c * BLK + t;
        int g = b * NN + j;
        size_t g3 = (size_t)g * 3;
        float x = 1e30f, y = 1e30f, z = 1e30f;  // invalid: loses every min, stays finite
        if (mask[g]) {
            x = points[g3 + 0] + dc[g3 + 0];
            y = points[g3 + 1] + dc[g3 + 1];
            z = points[g3 + 2] + dc[g3 + 2];
        }
        cand[j] = make_float4(x, y, z, 0.f);
    }

    // ---- wave w owns 8 consecutive queries (wave-uniform float4 loads) ----
    int qi0 = qs * QPB + w * Q;
    float qx[Q], qy[Q], qz[Q], mn[Q];
    {
        size_t g3 = (size_t)(b * NN + qi0) * 3;   // multiple of 24 -> 16B aligned
        const float4* p4 = (const float4*)(points + g3);
        const float4* d4 = (const float4*)(dq + g3);
        float a[24];
        #pragma unroll
        for (int r = 0; r < 6; ++r) {
            float4 pv = p4[r], dv = d4[r];
            a[4*r+0] = pv.x + dv.x; a[4*r+1] = pv.y + dv.y;
            a[4*r+2] = pv.z + dv.z; a[4*r+3] = pv.w + dv.w;
        }
        #pragma unroll
        for (int q = 0; q < Q; ++q) {
            qx[q] = a[3*q]; qy[q] = a[3*q+1]; qz[q] = a[3*q+2];
            mn[q] = FLT_MAX;
        }
    }
    __syncthreads();

    // ---- scan: lane handles strided candidate subset {jj*64 + lane} ----
    // ds_read_b128 wave-contiguous (1024B), conflict-free; serves 512 pairs/read
    #pragma unroll 4
    for (int jj = 0; jj < 32; jj += 2) {
        float4 c0 = cand[jj * 64 + lane];
        float4 c1 = cand[(jj + 1) * 64 + lane];
        #pragma unroll
        for (int q = 0; q < Q; ++q) {
            float d0 = fabsf(qx[q] - c0.x) + fabsf(qy[q] - c0.y) + fabsf(qz[q] - c0.z);
            float d1 = fabsf(qx[q] - c1.x) + fabsf(qy[q] - c1.y) + fabsf(qz[q] - c1.z);
            mn[q] = fminf(fminf(d0, d1), mn[q]);   // v_min3_f32; min is order-exact
        }
    }

    // ---- in-wave min-reduce: lane 0 gets the full min per query (no LDS) ----
    #pragma unroll
    for (int off = 32; off; off >>= 1) {
        #pragma unroll
        for (int q = 0; q < Q; ++q)
            mn[q] = fminf(mn[q], __shfl_down(mn[q], off, 64));
    }

    // ---- per-wave masked cham sum + fused L1/count (lane 0, static indices) ----
    __shared__ float lv[4], ls[4], lc[4];
    if (lane == 0) {
        float v = 0.f, sl1 = 0.f, scnt = 0.f;
        #pragma unroll
        for (int q = 0; q < Q; ++q) {
            int gq = b * NN + qi0 + q;
            float mf = (float)mask[gq];
            v += (mf != 0.f) ? mn[q] : 0.f;
            if (task == 0) {   // each point covered exactly once by task-0 blocks
                size_t g3 = (size_t)gq * 3;
                sl1 += (fabsf(pred[g3 + 0] - target[g3 + 0]) +
                        fabsf(pred[g3 + 1] - target[g3 + 1]) +
                        fabsf(pred[g3 + 2] - target[g3 + 2])) * (1.0f / 3.0f) * mf;
                scnt += mf;
            }
        }
        lv[w] = v; ls[w] = sl1; lc[w] = scnt;
    }
    __syncthreads();

    // ---- publish block partials (release stores), take monotonic ticket ----
    __shared__ int isLast;
    if (t == 0) {
        __hip_atomic_store(&cham[bid], lv[0] + lv[1] + lv[2] + lv[3],
                           __ATOMIC_RELEASE, __HIP_MEMORY_SCOPE_AGENT);
        if (task == 0) {
            __hip_atomic_store(&l1p[(b << 6) | qs], ls[0] + ls[1] + ls[2] + ls[3],
                               __ATOMIC_RELEASE, __HIP_MEMORY_SCOPE_AGENT);
            __hip_atomic_store(&cnt[(b << 6) | qs], lc[0] + lc[1] + lc[2] + lc[3],
                               __ATOMIC_RELEASE, __HIP_MEMORY_SCOPE_AGENT);
        }
        unsigned int tk = __hip_atomic_fetch_add(gcnt, 1u, __ATOMIC_ACQ_REL,
                                                 __HIP_MEMORY_SCOPE_AGENT);
        isLast = (((tk + 1u) & (NBLOCKS - 1)) == 0u);
    }
    __syncthreads();
    if (!isLast) return;

    // ---- finalize in the globally-last block (r9-proven, acquire loads) ----
    __shared__ float gsum[16];   // per-(task,b) chamfer sums
    __shared__ float cntb[8];    // per-b valid counts
    __shared__ float l1w[4];     // per-wave l1 partials

    #pragma unroll
    for (int r = 0; r < 4; ++r) {            // cham: 16 groups of 64 consecutive
        int g = w + r * 4;
        float x = __hip_atomic_load(&cham[(g << 6) | lane], __ATOMIC_ACQUIRE,
                                    __HIP_MEMORY_SCOPE_AGENT);
        for (int off = 32; off; off >>= 1) x += __shfl_down(x, off, 64);
        if (lane == 0) gsum[g] = x;
    }
    #pragma unroll
    for (int r = 0; r < 2; ++r) {            // cnt: 8 groups of 64 consecutive
        int g = w + r * 4;
        float x = __hip_atomic_load(&cnt[(g << 6) | lane], __ATOMIC_ACQUIRE,
                                    __HIP_MEMORY_SCOPE_AGENT);
        for (int off = 32; off; off >>= 1) x += __shfl_down(x, off, 64);
        if (lane == 0) cntb[g] = x;
    }
    {                                         // l1: wave w sums its 128 entries
        float x = __hip_atomic_load(&l1p[w * 128 + lane], __ATOMIC_ACQUIRE,
                                    __HIP_MEMORY_SCOPE_AGENT)
                + __hip_atomic_load(&l1p[w * 128 + 64 + lane], __ATOMIC_ACQUIRE,
                                    __HIP_MEMORY_SCOPE_AGENT);
        for (int off = 32; off; off >>= 1) x += __shfl_down(x, off, 64);
        if (lane == 0) l1w[w] = x;
    }
    __syncthreads();
    if (t == 0) {
        double l1num = (double)l1w[0] + (double)l1w[1] + (double)l1w[2] + (double)l1w[3];
        double msum = 0.0;
        for (int b2 = 0; b2 < BB; ++b2) msum += (double)cntb[b2];
        double l1 = l1num / msum;
        double cd = 0.0;
        for (int b2 = 0; b2 < BB; ++b2)
            cd += ((double)gsum[b2] + (double)gsum[8 + b2]) / (double)cntb[b2];
        cd *= (1.0 / BB);
        out[0] = (float)(l1 + exp(-l1) * cd);
    }
}

extern "C" void kernel_launch(void* const* d_in, const int* in_sizes, int n_in,
                              void* d_out, int out_size, void* d_ws, size_t ws_size,
                              hipStream_t stream) {
    const float* pred   = (const float*)d_in[0];
    const float* target = (const float*)d_in[1];
    const int*   mask   = (const int*)d_in[2];
    const float* points = (const float*)d_in[3];
    float* out = (float*)d_out;

    float* cham = (float*)d_ws;
    float* l1p  = (float*)((char*)d_ws + 4096);
    float* cnt  = (float*)((char*)d_ws + 6144);
    unsigned int* gcnt = (unsigned int*)((char*)d_ws + 8192);

    k_one<<<NBLOCKS, BLK, 0, stream>>>(pred, target, points, mask,
                                       cham, l1p, cnt, gcnt, out);
}